// Round 13
// baseline (83.079 us; speedup 1.0000x reference)
//
#include <hip/hip_runtime.h>

#define D 64
#define BSH 6            // bucket shift: 64 nodes per bucket
#define BSZ 64           // nodes per bucket
#define NBMAX 2048       // max buckets (nodes <= 131072)
#define TILE 8192        // edges per block in bucket passes (proven)
#define CAP  1536        // LDS edge-staging capacity (mean ~1024, 16 sigma)
#define SRTC (CAP + BSZ * 8 + 8)   // sorted+padded capacity (2056)

typedef unsigned int   uint;
typedef unsigned short ushort_t;
typedef __attribute__((ext_vector_type(8))) short bf16x8;
typedef __attribute__((ext_vector_type(4))) float f32x4;

__device__ __forceinline__ ushort_t f2bf(float f) {
    uint u = __float_as_uint(f);
    u += 0x7FFFu + ((u >> 16) & 1u);           // round-to-nearest-even
    return (ushort_t)(u >> 16);
}

// ---------------------------------------------------------------------------
// A1. Per-block bucket histogram (bucket = dst>>6); reserve per-block ranges.
//     Fused: converts a slice of x -> xb (bf16); block 0 zeroes xb row
//     n_nodes (the gather pad target).
// ---------------------------------------------------------------------------
__global__ __launch_bounds__(256) void k_bhist(
    const int* __restrict__ dst, int* __restrict__ bucketCount,
    int* __restrict__ blockBase, const float4* __restrict__ x4,
    uint4* __restrict__ xb4, int n8, int nb, int n_edges)
{
    __shared__ int hist[NBMAX];
    const int tid = threadIdx.x;
    for (int i = tid; i < nb; i += 256) hist[i] = 0;
    __syncthreads();

    // Zero row n_nodes of xb (pad rows gather from here).
    if (blockIdx.x == 0 && tid < 8) {
        uint4 z; z.x = z.y = z.z = z.w = 0u;
        xb4[n8 + tid] = z;
    }

    // Fused bf16 conversion slice.
    {
        const int chunk = (n8 + gridDim.x - 1) / gridDim.x;
        const int lo = blockIdx.x * chunk;
        const int hi = min(n8, lo + chunk);
        for (int t = lo + tid; t < hi; t += 256) {
            float4 a = x4[t * 2];
            float4 c = x4[t * 2 + 1];
            uint4 o;
            o.x = (uint)f2bf(a.x) | ((uint)f2bf(a.y) << 16);
            o.y = (uint)f2bf(a.z) | ((uint)f2bf(a.w) << 16);
            o.z = (uint)f2bf(c.x) | ((uint)f2bf(c.y) << 16);
            o.w = (uint)f2bf(c.z) | ((uint)f2bf(c.w) << 16);
            xb4[t] = o;
        }
    }

    const int e0 = blockIdx.x * TILE;
    const int n4 = n_edges >> 2;
    const int4* dst4 = (const int4*)dst;
#pragma unroll
    for (int k = 0; k < TILE / 1024; ++k) {
        int i4 = (e0 >> 2) + k * 256 + tid;
        if (i4 < n4) {
            int4 d = dst4[i4];
            atomicAdd(&hist[d.x >> BSH], 1);
            atomicAdd(&hist[d.y >> BSH], 1);
            atomicAdd(&hist[d.z >> BSH], 1);
            atomicAdd(&hist[d.w >> BSH], 1);
        }
    }
    if (blockIdx.x == gridDim.x - 1) {
        for (int e = (n4 << 2) + tid; e < n_edges; e += 256)
            atomicAdd(&hist[dst[e] >> BSH], 1);
    }
    __syncthreads();
    for (int i = tid; i < nb; i += 256)
        blockBase[(size_t)blockIdx.x * nb + i] = atomicAdd(&bucketCount[i], hist[i]);
}

// ---------------------------------------------------------------------------
// A2. Scatter packed (src | dstLocal<<24) into bucket-grouped runs.
//     Redundant per-block LDS scan of bucketCount (no serial k_bscan);
//     block 0 publishes bucketBase for k_aggcsr.
// ---------------------------------------------------------------------------
__global__ __launch_bounds__(256) void k_bscatter(
    const int* __restrict__ src, const int* __restrict__ dst,
    const int* __restrict__ bucketCount, const int* __restrict__ blockBase,
    int* __restrict__ bucketBase, int* __restrict__ packed,
    int nb, int n_edges)
{
    __shared__ int sc[NBMAX];     // exclusive bucket bases
    __shared__ int cur[NBMAX];
    __shared__ int ts[256];
    const int tid = threadIdx.x;
    const int blk = blockIdx.x;

    // Blocked exclusive scan of bucketCount[0..nb) (8 elems per thread).
    {
        const int base = tid * 8;
        int v[8];
#pragma unroll
        for (int k = 0; k < 8; ++k)
            v[k] = (base + k < nb) ? bucketCount[base + k] : 0;
        int tsum = 0;
#pragma unroll
        for (int k = 0; k < 8; ++k) tsum += v[k];
        ts[tid] = tsum;
        __syncthreads();
        for (int off = 1; off < 256; off <<= 1) {
            int t = (tid >= off) ? ts[tid - off] : 0;
            __syncthreads();
            ts[tid] += t;
            __syncthreads();
        }
        int run = ts[tid] - tsum;          // exclusive across threads
#pragma unroll
        for (int k = 0; k < 8; ++k) {
            if (base + k < nb) sc[base + k] = run;
            run += v[k];
        }
    }
    __syncthreads();

    if (blk == 0) {
        for (int i = tid; i <= nb; i += 256)
            bucketBase[i] = (i < nb) ? sc[i] : n_edges;
    }

    for (int i = tid; i < nb; i += 256)
        cur[i] = sc[i] + blockBase[(size_t)blk * nb + i];
    __syncthreads();

    const int e0 = blk * TILE;
    const int n4 = n_edges >> 2;
    const int4* src4 = (const int4*)src;
    const int4* dst4 = (const int4*)dst;
#pragma unroll
    for (int k = 0; k < TILE / 1024; ++k) {
        int i4 = (e0 >> 2) + k * 256 + tid;
        if (i4 < n4) {
            int4 sv = src4[i4];
            int4 dv = dst4[i4];
            int p;
            p = atomicAdd(&cur[dv.x >> BSH], 1); packed[p] = sv.x | ((dv.x & (BSZ-1)) << 24);
            p = atomicAdd(&cur[dv.y >> BSH], 1); packed[p] = sv.y | ((dv.y & (BSZ-1)) << 24);
            p = atomicAdd(&cur[dv.z >> BSH], 1); packed[p] = sv.z | ((dv.z & (BSZ-1)) << 24);
            p = atomicAdd(&cur[dv.w >> BSH], 1); packed[p] = sv.w | ((dv.w & (BSZ-1)) << 24);
        }
    }
    if (blk == gridDim.x - 1) {
        for (int e = (n4 << 2) + tid; e < n_edges; e += 256) {
            int p = atomicAdd(&cur[dst[e] >> BSH], 1);
            packed[p] = src[e] | ((dst[e] & (BSZ-1)) << 24);
        }
    }
}

// ---------------------------------------------------------------------------
// B. Fused per-bucket CSR + aggregate + MFMA GEMM + bias. One block per
//    64-node bucket (512 thr, 8 waves, ~23KB LDS). NEW: gather is software-
//    pipelined — issue next 8 loads, sched_barrier(0), consume previous 8.
//    The fence stops hipcc from sinking loads (r12: VGPR=24 proved it had),
//    giving ~16 outstanding loads/lane. __launch_bounds__(512,6) lifts the
//    register cap so the pipeline stays in VGPRs.
// ---------------------------------------------------------------------------
__global__ __launch_bounds__(512, 6) void k_aggcsr(
    const int* __restrict__ packed, const int* __restrict__ bucketBase,
    const uint2* __restrict__ xb2, const float* __restrict__ W,
    const float* __restrict__ bvec, float* __restrict__ out, int n_nodes)
{
    __shared__ int raw[CAP];
    __shared__ int srt[SRTC];             // sorted+padded; reused for h-staging
    __shared__ ushort_t Wl[64 * 64];      // bf16 W, XOR-swizzled rows
    __shared__ int ldeg[BSZ];
    __shared__ int lofs[BSZ];
    __shared__ int cur[BSZ];

    const int tid = threadIdx.x;
    const int bucket = blockIdx.x;
    const int ebase = bucketBase[bucket];
    const int ecnt  = bucketBase[bucket + 1] - ebase;
    const bool fits = (ecnt <= CAP);
    const uint nmax = (uint)(n_nodes - 1);
    const int zrow = n_nodes;             // zeroed xb row for padding

    // Phase 0: stage W (fp32 -> bf16) into LDS with byte ^= (row&7)<<4 swizzle.
    {
        const int o = tid >> 3;            // row 0..63
        const int j = (tid & 7) * 8;       // col 0..56
        const float* wp = W + o * 64 + j;
        float4 wa = *(const float4*)wp;
        float4 wb = *(const float4*)(wp + 4);
        uint4 w4;
        w4.x = (uint)f2bf(wa.x) | ((uint)f2bf(wa.y) << 16);
        w4.y = (uint)f2bf(wa.z) | ((uint)f2bf(wa.w) << 16);
        w4.z = (uint)f2bf(wb.x) | ((uint)f2bf(wb.y) << 16);
        w4.w = (uint)f2bf(wb.z) | ((uint)f2bf(wb.w) << 16);
        *(uint4*)((char*)Wl + o * 128 + ((j * 2) ^ ((o & 7) << 4))) = w4;
    }
    if (tid < BSZ) ldeg[tid] = 0;
    __syncthreads();

    // Phase 1: stage edges + degree histogram.
    if (fits) {
        for (int i = tid; i < ecnt; i += 512) {
            int pk = packed[ebase + i];
            raw[i] = pk;
            atomicAdd(&ldeg[((uint)pk) >> 24], 1);
        }
    } else {
        for (int i = tid; i < ecnt; i += 512)
            atomicAdd(&ldeg[((uint)packed[ebase + i]) >> 24], 1);
    }
    __syncthreads();

    // Phase 2: exclusive scan of PADDED counts (first 64 threads).
    {
        int v = 0;
        if (tid < BSZ) { v = (ldeg[tid] + 7) & ~7; lofs[tid] = v; }
        __syncthreads();
        for (int off = 1; off < BSZ; off <<= 1) {
            int t = (tid < BSZ && tid >= off) ? lofs[tid - off] : 0;
            __syncthreads();
            if (tid < BSZ) lofs[tid] += t;
            __syncthreads();
        }
        if (tid < BSZ) { int e = lofs[tid] - v; lofs[tid] = e; cur[tid] = e; }
    }
    __syncthreads();

    // Phase 3: sort esrc into padded LDS segments + fill pads with zrow.
    if (fits) {
        for (int i = tid; i < ecnt; i += 512) {
            int pk = raw[i];
            int pos = atomicAdd(&cur[((uint)pk) >> 24], 1);
            srt[pos] = pk & 0x00FFFFFF;
        }
        if (tid < BSZ) {
            int base = lofs[tid] + ldeg[tid];
            int end  = lofs[tid] + ((ldeg[tid] + 7) & ~7);
            for (int i = base; i < end; ++i) srt[i] = zrow;
        }
    }
    __syncthreads();

    // Phase 4: gather. Wave w owns nodes w*8..w*8+7 (2 passes x 4 groups).
    const int wave = tid >> 6;
    const int lane = tid & 63;
    const int g    = lane >> 4;        // node group 0..3
    const int fq   = lane & 15;        // feats fq*4 .. fq*4+3

#define CVLO(u) __uint_as_float((u) << 16)
#define CVHI(u) __uint_as_float((u) & 0xFFFF0000u)

    const uint2* __restrict__ xbf = xb2 + fq;

    uint2 hreg[2];
#pragma unroll
    for (int p = 0; p < 2; ++p) { hreg[p].x = 0u; hreg[p].y = 0u; }

#pragma unroll
    for (int p = 0; p < 2; ++p) {
        const int nl = wave * 8 + p * 4 + g;
        const int node = (bucket << BSH) + nl;
        const bool valid = (node < n_nodes);
        const int cnt = valid ? ldeg[nl] : 0;
        const int eb  = valid ? lofs[nl] : 0;
        const int pc  = (cnt + 7) & ~7;

        float s0 = 0.f, s1 = 0.f, s2 = 0.f, s3 = 0.f;

        if (fits) {
            if (pc > 0) {
                uint2 A[8];
                {
                    int vv[8];
#pragma unroll
                    for (int k = 0; k < 8; ++k) vv[k] = srt[eb + k];
#pragma unroll
                    for (int k = 0; k < 8; ++k)
                        A[k] = xbf[(size_t)(uint)vv[k] * 16];
                }
                for (int i = 8; i < pc; i += 8) {
                    uint2 B[8];
                    {
                        int nv[8];
#pragma unroll
                        for (int k = 0; k < 8; ++k) nv[k] = srt[eb + i + k];
#pragma unroll
                        for (int k = 0; k < 8; ++k)
                            B[k] = xbf[(size_t)(uint)nv[k] * 16];
                    }
                    __builtin_amdgcn_sched_barrier(0);   // keep B issued before A consumed
#pragma unroll
                    for (int k = 0; k < 8; ++k) {
                        s0 += CVLO(A[k].x);
                        s1 += CVHI(A[k].x);
                        s2 += CVLO(A[k].y);
                        s3 += CVHI(A[k].y);
                    }
#pragma unroll
                    for (int k = 0; k < 8; ++k) A[k] = B[k];
                }
#pragma unroll
                for (int k = 0; k < 8; ++k) {
                    s0 += CVLO(A[k].x);
                    s1 += CVHI(A[k].x);
                    s2 += CVLO(A[k].y);
                    s3 += CVHI(A[k].y);
                }
            }
        } else {
            // Fallback (never hit for this input): masked scan of bucket.
            const int nlm = valid ? nl : -1;
            for (int i = 0; i < ecnt; ++i) {
                int pk = packed[ebase + i];
                float m0 = ((int)(((uint)pk) >> 24) == nlm) ? 1.0f : 0.0f;
                uint2 A0 = xbf[(size_t)min((uint)(pk & 0x00FFFFFF), nmax) * 16];
                s0 = fmaf(m0, CVLO(A0.x), s0);
                s1 = fmaf(m0, CVHI(A0.x), s1);
                s2 = fmaf(m0, CVLO(A0.y), s2);
                s3 = fmaf(m0, CVHI(A0.y), s3);
            }
        }

        if (valid) {
            uint2 xv = xbf[(size_t)node * 16];        // bf16 self term
            float rinv = 1.0f / (float)(cnt + 1);
            float h0 = (s0 + CVLO(xv.x)) * rinv;
            float h1 = (s1 + CVHI(xv.x)) * rinv;
            float h2 = (s2 + CVLO(xv.y)) * rinv;
            float h3 = (s3 + CVHI(xv.y)) * rinv;
            hreg[p].x = (uint)f2bf(h0) | ((uint)f2bf(h1) << 16);
            hreg[p].y = (uint)f2bf(h2) | ((uint)f2bf(h3) << 16);
        }
    }
#undef CVLO
#undef CVHI

    // All waves done with srt -> reuse it as the shared 64x64 bf16 h tile.
    __syncthreads();

    char* hstage = (char*)srt;               // 64 rows x 128B, swizzled
#pragma unroll
    for (int p = 0; p < 2; ++p) {
        int nl = wave * 8 + p * 4 + g;       // row 0..63
        *(uint2*)(hstage + nl * 128 + ((fq * 8) ^ ((nl & 7) << 4))) = hreg[p];
    }
    __syncthreads();

    // MFMA epilogue: waves 0..3 each handle one 16-node tile.
    if (wave < 4) {
        char* hwb = hstage + wave * 2048;
        const int m  = lane & 15;
        const int kg = lane >> 4;
        bf16x8 a0 = *(const bf16x8*)(hwb + m * 128 + (((kg * 16)     ) ^ ((m & 7) << 4)));
        bf16x8 a1 = *(const bf16x8*)(hwb + m * 128 + (((64 + kg * 16)) ^ ((m & 7) << 4)));

        const int node0 = (bucket << BSH) + wave * 16;
#pragma unroll
        for (int c = 0; c < 4; ++c) {
            const int o = c * 16 + m;
            bf16x8 b0 = *(const bf16x8*)((char*)Wl + o * 128 + (((kg * 16)     ) ^ ((o & 7) << 4)));
            bf16x8 b1 = *(const bf16x8*)((char*)Wl + o * 128 + (((64 + kg * 16)) ^ ((o & 7) << 4)));
            f32x4 acc = {0.f, 0.f, 0.f, 0.f};
            acc = __builtin_amdgcn_mfma_f32_16x16x32_bf16(a0, b0, acc, 0, 0, 0);
            acc = __builtin_amdgcn_mfma_f32_16x16x32_bf16(a1, b1, acc, 0, 0, 0);
            const float bias = bvec[o];
#pragma unroll
            for (int r = 0; r < 4; ++r) {
                int row = node0 + kg * 4 + r;
                if (row < n_nodes)
                    out[(size_t)row * 64 + o] = acc[r] + bias;
            }
        }
    }
}

extern "C" void kernel_launch(void* const* d_in, const int* in_sizes, int n_in,
                              void* d_out, int out_size, void* d_ws, size_t ws_size,
                              hipStream_t stream)
{
    const float* x   = (const float*)d_in[0];
    const int*   src = (const int*)d_in[1];
    const int*   dst = (const int*)d_in[2];
    const float* W   = (const float*)d_in[3];
    const float* b   = (const float*)d_in[4];
    float* out = (float*)d_out;

    const int n_nodes = in_sizes[0] / D;
    const int n_edges = in_sizes[1];
    const int nb  = (n_nodes + BSZ - 1) >> BSH;      // 64-node buckets (1563)
    const int nbA = (n_edges + TILE - 1) / TILE;     // edge-pass blocks (196)

    // Workspace: [xb (N+1)*64 bf16][bucketCount NBMAX][bucketBase NBMAX+1]
    //            [blockBase nbA*nb][packed E]
    ushort_t* xb = (ushort_t*)d_ws;
    int* bucketCount = (int*)(xb + (size_t)(n_nodes + 1) * D);
    int* bucketBase  = bucketCount + NBMAX;
    int* blockBase   = bucketBase + NBMAX + 1;
    int* packed      = blockBase + (size_t)nbA * nb;

    hipMemsetAsync(bucketCount, 0, NBMAX * sizeof(int), stream);

    const int n8 = n_nodes * D / 8;
    k_bhist   <<<nbA, 256, 0, stream>>>(dst, bucketCount, blockBase,
                                        (const float4*)x, (uint4*)xb, n8, nb, n_edges);
    k_bscatter<<<nbA, 256, 0, stream>>>(src, dst, bucketCount, blockBase,
                                        bucketBase, packed, nb, n_edges);
    k_aggcsr  <<<nb,  512, 0, stream>>>(packed, bucketBase, (const uint2*)xb,
                                        W, b, out, n_nodes);
}

// Round 14
// 78.219 us; speedup vs baseline: 1.0621x; 1.0621x over previous
//
#include <hip/hip_runtime.h>

#define D 64
#define BSH 6            // bucket shift: 64 nodes per bucket
#define BSZ 64           // nodes per bucket
#define NBMAX 2048       // max buckets (nodes <= 131072)
#define TILE 8192        // edges per block in bucket passes (proven)
#define CAP  1536        // LDS edge-staging capacity (mean ~1024, 16 sigma)
#define SRTC 2056        // sorted+padded capacity (>= 8KB for h-staging reuse)

typedef unsigned int   uint;
typedef unsigned short ushort_t;
typedef __attribute__((ext_vector_type(8))) short bf16x8;
typedef __attribute__((ext_vector_type(4))) float f32x4;

__device__ __forceinline__ ushort_t f2bf(float f) {
    uint u = __float_as_uint(f);
    u += 0x7FFFu + ((u >> 16) & 1u);           // round-to-nearest-even
    return (ushort_t)(u >> 16);
}

// ---------------------------------------------------------------------------
// A1. Per-block bucket histogram (bucket = dst>>6); reserve per-block ranges.
//     Fused: converts a slice of x -> xb (bf16); block 0 zeroes xb row
//     n_nodes (the gather pad target).
// ---------------------------------------------------------------------------
__global__ __launch_bounds__(256) void k_bhist(
    const int* __restrict__ dst, int* __restrict__ bucketCount,
    int* __restrict__ blockBase, const float4* __restrict__ x4,
    uint4* __restrict__ xb4, int n8, int nb, int n_edges)
{
    __shared__ int hist[NBMAX];
    const int tid = threadIdx.x;
    for (int i = tid; i < nb; i += 256) hist[i] = 0;
    __syncthreads();

    // Zero row n_nodes of xb (pad rows gather from here).
    if (blockIdx.x == 0 && tid < 8) {
        uint4 z; z.x = z.y = z.z = z.w = 0u;
        xb4[n8 + tid] = z;
    }

    // Fused bf16 conversion slice.
    {
        const int chunk = (n8 + gridDim.x - 1) / gridDim.x;
        const int lo = blockIdx.x * chunk;
        const int hi = min(n8, lo + chunk);
        for (int t = lo + tid; t < hi; t += 256) {
            float4 a = x4[t * 2];
            float4 c = x4[t * 2 + 1];
            uint4 o;
            o.x = (uint)f2bf(a.x) | ((uint)f2bf(a.y) << 16);
            o.y = (uint)f2bf(a.z) | ((uint)f2bf(a.w) << 16);
            o.z = (uint)f2bf(c.x) | ((uint)f2bf(c.y) << 16);
            o.w = (uint)f2bf(c.z) | ((uint)f2bf(c.w) << 16);
            xb4[t] = o;
        }
    }

    const int e0 = blockIdx.x * TILE;
    const int n4 = n_edges >> 2;
    const int4* dst4 = (const int4*)dst;
#pragma unroll
    for (int k = 0; k < TILE / 1024; ++k) {
        int i4 = (e0 >> 2) + k * 256 + tid;
        if (i4 < n4) {
            int4 d = dst4[i4];
            atomicAdd(&hist[d.x >> BSH], 1);
            atomicAdd(&hist[d.y >> BSH], 1);
            atomicAdd(&hist[d.z >> BSH], 1);
            atomicAdd(&hist[d.w >> BSH], 1);
        }
    }
    if (blockIdx.x == gridDim.x - 1) {
        for (int e = (n4 << 2) + tid; e < n_edges; e += 256)
            atomicAdd(&hist[dst[e] >> BSH], 1);
    }
    __syncthreads();
    for (int i = tid; i < nb; i += 256)
        blockBase[(size_t)blockIdx.x * nb + i] = atomicAdd(&bucketCount[i], hist[i]);
}

// ---------------------------------------------------------------------------
// A2. Scatter packed (src | dstLocal<<24) into bucket-grouped runs.
//     Redundant per-block LDS scan of bucketCount (no serial k_bscan);
//     block 0 publishes bucketBase for k_aggcsr.
// ---------------------------------------------------------------------------
__global__ __launch_bounds__(256) void k_bscatter(
    const int* __restrict__ src, const int* __restrict__ dst,
    const int* __restrict__ bucketCount, const int* __restrict__ blockBase,
    int* __restrict__ bucketBase, int* __restrict__ packed,
    int nb, int n_edges)
{
    __shared__ int sc[NBMAX];     // exclusive bucket bases
    __shared__ int cur[NBMAX];
    __shared__ int ts[256];
    const int tid = threadIdx.x;
    const int blk = blockIdx.x;

    // Blocked exclusive scan of bucketCount[0..nb) (8 elems per thread).
    {
        const int base = tid * 8;
        int v[8];
#pragma unroll
        for (int k = 0; k < 8; ++k)
            v[k] = (base + k < nb) ? bucketCount[base + k] : 0;
        int tsum = 0;
#pragma unroll
        for (int k = 0; k < 8; ++k) tsum += v[k];
        ts[tid] = tsum;
        __syncthreads();
        for (int off = 1; off < 256; off <<= 1) {
            int t = (tid >= off) ? ts[tid - off] : 0;
            __syncthreads();
            ts[tid] += t;
            __syncthreads();
        }
        int run = ts[tid] - tsum;          // exclusive across threads
#pragma unroll
        for (int k = 0; k < 8; ++k) {
            if (base + k < nb) sc[base + k] = run;
            run += v[k];
        }
    }
    __syncthreads();

    if (blk == 0) {
        for (int i = tid; i <= nb; i += 256)
            bucketBase[i] = (i < nb) ? sc[i] : n_edges;
    }

    for (int i = tid; i < nb; i += 256)
        cur[i] = sc[i] + blockBase[(size_t)blk * nb + i];
    __syncthreads();

    const int e0 = blk * TILE;
    const int n4 = n_edges >> 2;
    const int4* src4 = (const int4*)src;
    const int4* dst4 = (const int4*)dst;
#pragma unroll
    for (int k = 0; k < TILE / 1024; ++k) {
        int i4 = (e0 >> 2) + k * 256 + tid;
        if (i4 < n4) {
            int4 sv = src4[i4];
            int4 dv = dst4[i4];
            int p;
            p = atomicAdd(&cur[dv.x >> BSH], 1); packed[p] = sv.x | ((dv.x & (BSZ-1)) << 24);
            p = atomicAdd(&cur[dv.y >> BSH], 1); packed[p] = sv.y | ((dv.y & (BSZ-1)) << 24);
            p = atomicAdd(&cur[dv.z >> BSH], 1); packed[p] = sv.z | ((dv.z & (BSZ-1)) << 24);
            p = atomicAdd(&cur[dv.w >> BSH], 1); packed[p] = sv.w | ((dv.w & (BSZ-1)) << 24);
        }
    }
    if (blk == gridDim.x - 1) {
        for (int e = (n4 << 2) + tid; e < n_edges; e += 256) {
            int p = atomicAdd(&cur[dst[e] >> BSH], 1);
            packed[p] = src[e] | ((dst[e] & (BSZ-1)) << 24);
        }
    }
}

// ---------------------------------------------------------------------------
// B. Fused per-bucket CSR + aggregate + MFMA GEMM + bias. One block per
//    64-node bucket (512 thr, 8 waves, ~23KB LDS -> 4 blocks/CU, 32 waves).
//    Phase 4 NEW layout: 8 edge-groups x 8 lanes, uint4 loads (16B/lane) —
//    one wave load instruction covers 8 cache lines (vs 4 before), halving
//    memory-instruction count per edge and doubling lines-in-flight per
//    outstanding load. Serial per-node walk, no cross-lane reduce, pad to
//    multiple of 4 with the zero row.
// ---------------------------------------------------------------------------
__global__ __launch_bounds__(512, 8) void k_aggcsr(
    const int* __restrict__ packed, const int* __restrict__ bucketBase,
    const uint4* __restrict__ xb4, const float* __restrict__ W,
    const float* __restrict__ bvec, float* __restrict__ out, int n_nodes)
{
    __shared__ int raw[CAP];
    __shared__ int srt[SRTC];             // sorted+padded; reused for h-staging
    __shared__ ushort_t Wl[64 * 64];      // bf16 W, XOR-swizzled rows
    __shared__ int ldeg[BSZ];
    __shared__ int lofs[BSZ];
    __shared__ int cur[BSZ];

    const int tid = threadIdx.x;
    const int bucket = blockIdx.x;
    const int ebase = bucketBase[bucket];
    const int ecnt  = bucketBase[bucket + 1] - ebase;
    const bool fits = (ecnt <= CAP);
    const uint nmax = (uint)(n_nodes - 1);
    const int zrow = n_nodes;             // zeroed xb row for padding

    // Phase 0: stage W (fp32 -> bf16) into LDS with byte ^= (row&7)<<4 swizzle.
    {
        const int o = tid >> 3;            // row 0..63
        const int j = (tid & 7) * 8;       // col 0..56
        const float* wp = W + o * 64 + j;
        float4 wa = *(const float4*)wp;
        float4 wb = *(const float4*)(wp + 4);
        uint4 w4;
        w4.x = (uint)f2bf(wa.x) | ((uint)f2bf(wa.y) << 16);
        w4.y = (uint)f2bf(wa.z) | ((uint)f2bf(wa.w) << 16);
        w4.z = (uint)f2bf(wb.x) | ((uint)f2bf(wb.y) << 16);
        w4.w = (uint)f2bf(wb.z) | ((uint)f2bf(wb.w) << 16);
        *(uint4*)((char*)Wl + o * 128 + ((j * 2) ^ ((o & 7) << 4))) = w4;
    }
    if (tid < BSZ) ldeg[tid] = 0;
    __syncthreads();

    // Phase 1: stage edges + degree histogram.
    if (fits) {
        for (int i = tid; i < ecnt; i += 512) {
            int pk = packed[ebase + i];
            raw[i] = pk;
            atomicAdd(&ldeg[((uint)pk) >> 24], 1);
        }
    } else {
        for (int i = tid; i < ecnt; i += 512)
            atomicAdd(&ldeg[((uint)packed[ebase + i]) >> 24], 1);
    }
    __syncthreads();

    // Phase 2: exclusive scan of counts padded to multiple of 4 (first 64 thr).
    {
        int v = 0;
        if (tid < BSZ) { v = (ldeg[tid] + 3) & ~3; lofs[tid] = v; }
        __syncthreads();
        for (int off = 1; off < BSZ; off <<= 1) {
            int t = (tid < BSZ && tid >= off) ? lofs[tid - off] : 0;
            __syncthreads();
            if (tid < BSZ) lofs[tid] += t;
            __syncthreads();
        }
        if (tid < BSZ) { int e = lofs[tid] - v; lofs[tid] = e; cur[tid] = e; }
    }
    __syncthreads();

    // Phase 3: sort esrc into padded LDS segments + fill pads with zrow.
    if (fits) {
        for (int i = tid; i < ecnt; i += 512) {
            int pk = raw[i];
            int pos = atomicAdd(&cur[((uint)pk) >> 24], 1);
            srt[pos] = pk & 0x00FFFFFF;
        }
        if (tid < BSZ) {
            int base = lofs[tid] + ldeg[tid];
            int end  = lofs[tid] + ((ldeg[tid] + 3) & ~3);
            for (int i = base; i < end; ++i) srt[i] = zrow;
        }
    }
    __syncthreads();

    // Phase 4: gather. Wave w owns nodes w*8..w*8+7; group g (8 lanes) walks
    // node w*8+g serially, each lane holding 8 feats (uint4 = one half-row
    // per 8-lane group... full 128B row per group per edge).
    const int wave = tid >> 6;
    const int lane = tid & 63;
    const int g    = lane >> 3;        // node group 0..7
    const int f8   = lane & 7;         // uint4 index within row (8 feats)

#define CVLO(u) __uint_as_float((u) << 16)
#define CVHI(u) __uint_as_float((u) & 0xFFFF0000u)

    const uint4* __restrict__ xbf = xb4 + f8;

    const int nl = wave * 8 + g;
    const int node = (bucket << BSH) + nl;
    const bool valid = (node < n_nodes);
    const int cnt = valid ? ldeg[nl] : 0;
    const int eb  = valid ? lofs[nl] : 0;
    const int pc  = (cnt + 3) & ~3;

    float s0 = 0.f, s1 = 0.f, s2 = 0.f, s3 = 0.f;
    float s4 = 0.f, s5 = 0.f, s6 = 0.f, s7 = 0.f;

    if (fits) {
        for (int i = 0; i < pc; i += 4) {
            uint vv[4];
#pragma unroll
            for (int k = 0; k < 4; ++k) vv[k] = (uint)srt[eb + i + k];
            uint4 A[4];
#pragma unroll
            for (int k = 0; k < 4; ++k)
                A[k] = xbf[(size_t)vv[k] * 8];
#pragma unroll
            for (int k = 0; k < 4; ++k) {
                s0 += CVLO(A[k].x);
                s1 += CVHI(A[k].x);
                s2 += CVLO(A[k].y);
                s3 += CVHI(A[k].y);
                s4 += CVLO(A[k].z);
                s5 += CVHI(A[k].z);
                s6 += CVLO(A[k].w);
                s7 += CVHI(A[k].w);
            }
        }
    } else {
        // Fallback (never hit for this input): masked scan of bucket.
        const int nlm = valid ? nl : -1;
        for (int i = 0; i < ecnt; ++i) {
            int pk = packed[ebase + i];
            float m0 = ((int)(((uint)pk) >> 24) == nlm) ? 1.0f : 0.0f;
            uint4 A0 = xbf[(size_t)min((uint)(pk & 0x00FFFFFF), nmax) * 8];
            s0 = fmaf(m0, CVLO(A0.x), s0);
            s1 = fmaf(m0, CVHI(A0.x), s1);
            s2 = fmaf(m0, CVLO(A0.y), s2);
            s3 = fmaf(m0, CVHI(A0.y), s3);
            s4 = fmaf(m0, CVLO(A0.z), s4);
            s5 = fmaf(m0, CVHI(A0.z), s5);
            s6 = fmaf(m0, CVLO(A0.w), s6);
            s7 = fmaf(m0, CVHI(A0.w), s7);
        }
    }

    uint4 hreg; hreg.x = hreg.y = hreg.z = hreg.w = 0u;
    if (valid) {
        uint4 xv = xbf[(size_t)node * 8];            // bf16 self term
        float rinv = 1.0f / (float)(cnt + 1);
        float h0 = (s0 + CVLO(xv.x)) * rinv;
        float h1 = (s1 + CVHI(xv.x)) * rinv;
        float h2 = (s2 + CVLO(xv.y)) * rinv;
        float h3 = (s3 + CVHI(xv.y)) * rinv;
        float h4 = (s4 + CVLO(xv.z)) * rinv;
        float h5 = (s5 + CVHI(xv.z)) * rinv;
        float h6 = (s6 + CVLO(xv.w)) * rinv;
        float h7 = (s7 + CVHI(xv.w)) * rinv;
        hreg.x = (uint)f2bf(h0) | ((uint)f2bf(h1) << 16);
        hreg.y = (uint)f2bf(h2) | ((uint)f2bf(h3) << 16);
        hreg.z = (uint)f2bf(h4) | ((uint)f2bf(h5) << 16);
        hreg.w = (uint)f2bf(h6) | ((uint)f2bf(h7) << 16);
    }
#undef CVLO
#undef CVHI

    // All waves done with srt -> reuse it as the shared 64x64 bf16 h tile.
    __syncthreads();

    char* hstage = (char*)srt;               // 64 rows x 128B, swizzled
    *(uint4*)(hstage + nl * 128 + ((f8 * 16) ^ ((nl & 7) << 4))) = hreg;
    __syncthreads();

    // MFMA epilogue: waves 0..3 each handle one 16-node tile.
    if (wave < 4) {
        char* hwb = hstage + wave * 2048;
        const int m  = lane & 15;
        const int kg = lane >> 4;
        bf16x8 a0 = *(const bf16x8*)(hwb + m * 128 + (((kg * 16)     ) ^ ((m & 7) << 4)));
        bf16x8 a1 = *(const bf16x8*)(hwb + m * 128 + (((64 + kg * 16)) ^ ((m & 7) << 4)));

        const int node0 = (bucket << BSH) + wave * 16;
#pragma unroll
        for (int c = 0; c < 4; ++c) {
            const int o = c * 16 + m;
            bf16x8 b0 = *(const bf16x8*)((char*)Wl + o * 128 + (((kg * 16)     ) ^ ((o & 7) << 4)));
            bf16x8 b1 = *(const bf16x8*)((char*)Wl + o * 128 + (((64 + kg * 16)) ^ ((o & 7) << 4)));
            f32x4 acc = {0.f, 0.f, 0.f, 0.f};
            acc = __builtin_amdgcn_mfma_f32_16x16x32_bf16(a0, b0, acc, 0, 0, 0);
            acc = __builtin_amdgcn_mfma_f32_16x16x32_bf16(a1, b1, acc, 0, 0, 0);
            const float bias = bvec[o];
#pragma unroll
            for (int r = 0; r < 4; ++r) {
                int row = node0 + kg * 4 + r;
                if (row < n_nodes)
                    out[(size_t)row * 64 + o] = acc[r] + bias;
            }
        }
    }
}

extern "C" void kernel_launch(void* const* d_in, const int* in_sizes, int n_in,
                              void* d_out, int out_size, void* d_ws, size_t ws_size,
                              hipStream_t stream)
{
    const float* x   = (const float*)d_in[0];
    const int*   src = (const int*)d_in[1];
    const int*   dst = (const int*)d_in[2];
    const float* W   = (const float*)d_in[3];
    const float* b   = (const float*)d_in[4];
    float* out = (float*)d_out;

    const int n_nodes = in_sizes[0] / D;
    const int n_edges = in_sizes[1];
    const int nb  = (n_nodes + BSZ - 1) >> BSH;      // 64-node buckets (1563)
    const int nbA = (n_edges + TILE - 1) / TILE;     // edge-pass blocks (196)

    // Workspace: [xb (N+1)*64 bf16][bucketCount NBMAX][bucketBase NBMAX+1]
    //            [blockBase nbA*nb][packed E]
    ushort_t* xb = (ushort_t*)d_ws;
    int* bucketCount = (int*)(xb + (size_t)(n_nodes + 1) * D);
    int* bucketBase  = bucketCount + NBMAX;
    int* blockBase   = bucketBase + NBMAX + 1;
    int* packed      = blockBase + (size_t)nbA * nb;

    hipMemsetAsync(bucketCount, 0, NBMAX * sizeof(int), stream);

    const int n8 = n_nodes * D / 8;
    k_bhist   <<<nbA, 256, 0, stream>>>(dst, bucketCount, blockBase,
                                        (const float4*)x, (uint4*)xb, n8, nb, n_edges);
    k_bscatter<<<nbA, 256, 0, stream>>>(src, dst, bucketCount, blockBase,
                                        bucketBase, packed, nb, n_edges);
    k_aggcsr  <<<nb,  512, 0, stream>>>(packed, bucketBase, (const uint4*)xb,
                                        W, b, out, n_nodes);
}